// Round 3
// baseline (1723.820 us; speedup 1.0000x reference)
//
#include <hip/hip_runtime.h>

#define NN 120000
#define DD 64
#define EE 1000000
#define NL 3
#define OUTD 256     // (NL+1)*DD
#define PAD 68       // LDS row pad: float4-aligned, 2-way bank aliasing only (free)
#define NB 469       // ceil(NN/256)

// ---------------- CSR build ----------------

__global__ void k_degcnt(const int* __restrict__ row, const int* __restrict__ col,
                         int* __restrict__ deg_i, int* __restrict__ cnt) {
    int i = blockIdx.x * blockDim.x + threadIdx.x;
    int stride = gridDim.x * blockDim.x;
    for (int e = i; e < EE; e += stride) {
        atomicAdd(&deg_i[col[e]], 1);
        atomicAdd(&cnt[row[e]], 1);
    }
}

__global__ void k_dinv(const int* __restrict__ deg_i, float* __restrict__ dinv) {
    int n = blockIdx.x * blockDim.x + threadIdx.x;
    if (n < NN) {
        int d = deg_i[n];
        dinv[n] = (d > 0) ? rsqrtf((float)d) : 0.0f;
    }
}

__global__ void k_scanA(const int* __restrict__ cnt, int* __restrict__ row_ptr,
                        int* __restrict__ bsum) {
    __shared__ int sc[256];
    int t = threadIdx.x;
    int i = blockIdx.x * 256 + t;
    int v = (i < NN) ? cnt[i] : 0;
    sc[t] = v;
    __syncthreads();
    for (int off = 1; off < 256; off <<= 1) {
        int u = (t >= off) ? sc[t - off] : 0;
        __syncthreads();
        sc[t] += u;
        __syncthreads();
    }
    if (i < NN) row_ptr[i] = sc[t] - v;
    if (t == 255) bsum[blockIdx.x] = sc[255];
}

__global__ void k_scanB(int* __restrict__ bsum, int* __restrict__ row_ptr) {
    __shared__ int sc[512];
    int t = threadIdx.x;
    int v = (t < NB) ? bsum[t] : 0;
    sc[t] = v;
    __syncthreads();
    for (int off = 1; off < 512; off <<= 1) {
        int u = (t >= off) ? sc[t - off] : 0;
        __syncthreads();
        sc[t] += u;
        __syncthreads();
    }
    if (t < NB) bsum[t] = sc[t] - v;
    if (t == 0) row_ptr[NN] = EE;
}

__global__ void k_scanC(int* __restrict__ row_ptr, const int* __restrict__ bsum) {
    int i = blockIdx.x * blockDim.x + threadIdx.x;
    if (i < NN) row_ptr[i] += bsum[i >> 8];
}

// fill CSR: entry = { bits = (col<<6)|(row&63), dinv[col] }; also c[n] = sum norm
__global__ void k_fill(const int* __restrict__ row, const int* __restrict__ col,
                       const float* __restrict__ dinv, const int* __restrict__ row_ptr,
                       int* __restrict__ fill, float2* __restrict__ csr,
                       float* __restrict__ cbuf) {
    int i = blockIdx.x * blockDim.x + threadIdx.x;
    int stride = gridDim.x * blockDim.x;
    for (int e = i; e < EE; e += stride) {
        int r = row[e], c = col[e];
        float dr = dinv[r], dc = dinv[c];
        int pos = row_ptr[r] + atomicAdd(&fill[r], 1);
        csr[pos] = make_float2(__int_as_float((c << 6) | (r & 63)), dc);
        atomicAdd(&cbuf[r], dr * dc);
    }
}

__global__ void k_copy_emb(const float* __restrict__ emb, float* __restrict__ out) {
    int i = blockIdx.x * blockDim.x + threadIdx.x;
    int stride = gridDim.x * blockDim.x;
    const float4* e4 = (const float4*)emb;
    float4* o4 = (float4*)out;
    const int total = NN * (DD / 4);
    for (int t = i; t < total; t += stride) {
        int n = t >> 4;
        int d4 = t & 15;
        o4[n * (OUTD / 4) + d4] = e4[t];
    }
}

// ---------------- fused per-layer ----------------
// Block = 256 threads = 4 waves, owns 64 consecutive nodes (CSR rows contiguous).
// Phase 1: waves split the block's flat edge range; unroll x8 -> 8 gathers in
//          flight/wave; accumulate into LDS via ds_add_f32 (conflict-free).
// Phase 2: S1 = dinv[r] * lds; P = S1 * x (x re-read coalesced, L1-hot);
//          4x4 register microtile GEMM vs W1^T/W2^T; bias via precomputed c[n].

__global__ void __launch_bounds__(256, 6) k_layer(
    const int* __restrict__ row_ptr, const float2* __restrict__ csr,
    const float* __restrict__ dinv, const float* __restrict__ cbuf,
    const float* __restrict__ W1, const float* __restrict__ b1,
    const float* __restrict__ W2, const float* __restrict__ b2,
    float* __restrict__ out, int layer)
{
    __shared__ float s1t[64][PAD];

    const int lane = threadIdx.x & 63;
    const int wib  = threadIdx.x >> 6;
    const int n0   = blockIdx.x * 64;
    const float* __restrict__ x = out + layer * DD;      // row n at x[n*OUTD + d]

    // zero accumulation tile
    #pragma unroll
    for (int i = 0; i < 16; ++i) s1t[wib * 16 + i][lane] = 0.f;
    __syncthreads();

    // ---- phase 1: flat edge gather ----
    const int beg = row_ptr[n0];
    const int end = row_ptr[n0 + 64];
    const int per = (end - beg + 3) >> 2;
    int e0 = beg + wib * per;
    int e1 = min(end, e0 + per);

    int e = e0;
    for (; e + 8 <= e1; e += 8) {
        float2 q[8];
        #pragma unroll
        for (int u = 0; u < 8; ++u) q[u] = csr[e + u];
        float v[8];
        #pragma unroll
        for (int u = 0; u < 8; ++u)
            v[u] = q[u].y * x[(__float_as_int(q[u].x) >> 6) * OUTD + lane];
        #pragma unroll
        for (int u = 0; u < 8; ++u)
            atomicAdd(&s1t[__float_as_int(q[u].x) & 63][lane], v[u]);
    }
    for (; e < e1; ++e) {
        float2 q = csr[e];
        float v = q.y * x[(__float_as_int(q.x) >> 6) * OUTD + lane];
        atomicAdd(&s1t[__float_as_int(q.x) & 63][lane], v);
    }
    __syncthreads();

    // ---- phase 2: agg = S1@W1^T + (S1*x)@W2^T + c*(b1+b2) ----
    const int tf = threadIdx.x & 15;
    const int tn = threadIdx.x >> 4;
    const float* __restrict__ W1l = W1 + layer * DD * DD;
    const float* __restrict__ W2l = W2 + layer * DD * DD;

    float dv[4];
    #pragma unroll
    for (int i = 0; i < 4; ++i) dv[i] = dinv[n0 + 4 * tn + i];

    float acc[4][4];
    #pragma unroll
    for (int i = 0; i < 4; ++i)
        #pragma unroll
        for (int j = 0; j < 4; ++j) acc[i][j] = 0.f;

    for (int k4 = 0; k4 < 16; ++k4) {
        float4 a[4], p[4];
        #pragma unroll
        for (int i = 0; i < 4; ++i) {
            int nl = 4 * tn + i;
            float4 s  = *(const float4*)&s1t[nl][4 * k4];
            float4 xv = *(const float4*)&x[(size_t)(n0 + nl) * OUTD + 4 * k4];
            a[i].x = s.x * dv[i]; a[i].y = s.y * dv[i];
            a[i].z = s.z * dv[i]; a[i].w = s.w * dv[i];
            p[i].x = a[i].x * xv.x; p[i].y = a[i].y * xv.y;
            p[i].z = a[i].z * xv.z; p[i].w = a[i].w * xv.w;
        }
        #pragma unroll
        for (int j = 0; j < 4; ++j) {
            float4 wa = *(const float4*)&W1l[(4 * tf + j) * DD + 4 * k4];
            float4 wb = *(const float4*)&W2l[(4 * tf + j) * DD + 4 * k4];
            #pragma unroll
            for (int i = 0; i < 4; ++i) {
                acc[i][j] += a[i].x * wa.x + a[i].y * wa.y
                           + a[i].z * wa.z + a[i].w * wa.w
                           + p[i].x * wb.x + p[i].y * wb.y
                           + p[i].z * wb.z + p[i].w * wb.w;
            }
        }
    }

    float bbj[4];
    #pragma unroll
    for (int j = 0; j < 4; ++j) {
        int f = 4 * tf + j;
        bbj[j] = b1[layer * DD + f] + b2[layer * DD + f];
    }
    #pragma unroll
    for (int i = 0; i < 4; ++i) {
        int n = n0 + 4 * tn + i;
        float c = cbuf[n];
        float4 r;
        float t0 = acc[i][0] + c * bbj[0]; r.x = t0 >= 0.f ? t0 : 0.2f * t0;
        float t1 = acc[i][1] + c * bbj[1]; r.y = t1 >= 0.f ? t1 : 0.2f * t1;
        float t2 = acc[i][2] + c * bbj[2]; r.z = t2 >= 0.f ? t2 : 0.2f * t2;
        float t3 = acc[i][3] + c * bbj[3]; r.w = t3 >= 0.f ? t3 : 0.2f * t3;
        *(float4*)&out[(size_t)n * OUTD + (layer + 1) * DD + 4 * tf] = r;
    }
}

// ---------------- launch ----------------

extern "C" void kernel_launch(void* const* d_in, const int* in_sizes, int n_in,
                              void* d_out, int out_size, void* d_ws, size_t ws_size,
                              hipStream_t stream) {
    const int*   ei  = (const int*)d_in[0];
    const float* emb = (const float*)d_in[1];
    const float* W1  = (const float*)d_in[2];
    const float* b1  = (const float*)d_in[3];
    const float* W2  = (const float*)d_in[4];
    const float* b2  = (const float*)d_in[5];
    float* out = (float*)d_out;

    const int* row = ei;
    const int* col = ei + EE;

    // workspace layout
    float2* csr  = (float2*)d_ws;                 // EE float2 (8 MB)
    int* ibase   = (int*)(csr + EE);
    int* deg_i   = ibase;                         // NN
    int* cnt     = deg_i + NN;                    // NN
    int* fill    = cnt + NN;                      // NN
    float* cbuf  = (float*)(fill + NN);           // NN  (zeroed with the ints)
    int* row_ptr = (int*)(cbuf + NN);             // NN+1
    int* bsum    = row_ptr + NN + 1;              // 512
    float* dinv  = (float*)(bsum + 512);          // NN

    hipMemsetAsync(ibase, 0, (size_t)4 * NN * sizeof(int), stream);

    k_degcnt<<<1024, 256, 0, stream>>>(row, col, deg_i, cnt);
    k_dinv<<<NB, 256, 0, stream>>>(deg_i, dinv);
    k_scanA<<<NB, 256, 0, stream>>>(cnt, row_ptr, bsum);
    k_scanB<<<1, 512, 0, stream>>>(bsum, row_ptr);
    k_scanC<<<NB, 256, 0, stream>>>(row_ptr, bsum);
    k_fill<<<1024, 256, 0, stream>>>(row, col, dinv, row_ptr, fill, csr, cbuf);
    k_copy_emb<<<2048, 256, 0, stream>>>(emb, out);

    for (int layer = 0; layer < NL; ++layer) {
        k_layer<<<NN / 64, 256, 0, stream>>>(row_ptr, csr, dinv, cbuf,
                                             W1, b1, W2, b2, out, layer);
    }
}

// Round 6
// 1473.543 us; speedup vs baseline: 1.1698x; 1.1698x over previous
//
#include <hip/hip_runtime.h>

#define NN 120000
#define DD 64
#define EE 1000000
#define NL 3
#define OUTD 256     // (NL+1)*DD
#define PAD 68       // LDS row pad: float4-aligned, 2-way bank aliasing only (free)
#define NB 469       // ceil(NN/256)

// ---------------- CSR build ----------------

__global__ void k_degcnt(const int* __restrict__ row, const int* __restrict__ col,
                         int* __restrict__ deg_i, int* __restrict__ cnt) {
    int i = blockIdx.x * blockDim.x + threadIdx.x;
    int stride = gridDim.x * blockDim.x;
    for (int e = i; e < EE; e += stride) {
        atomicAdd(&deg_i[col[e]], 1);
        atomicAdd(&cnt[row[e]], 1);
    }
}

__global__ void k_dinv(const int* __restrict__ deg_i, float* __restrict__ dinv) {
    int n = blockIdx.x * blockDim.x + threadIdx.x;
    if (n < NN) {
        int d = deg_i[n];
        dinv[n] = (d > 0) ? rsqrtf((float)d) : 0.0f;
    }
}

__global__ void k_scanA(const int* __restrict__ cnt, int* __restrict__ row_ptr,
                        int* __restrict__ bsum) {
    __shared__ int sc[256];
    int t = threadIdx.x;
    int i = blockIdx.x * 256 + t;
    int v = (i < NN) ? cnt[i] : 0;
    sc[t] = v;
    __syncthreads();
    for (int off = 1; off < 256; off <<= 1) {
        int u = (t >= off) ? sc[t - off] : 0;
        __syncthreads();
        sc[t] += u;
        __syncthreads();
    }
    if (i < NN) row_ptr[i] = sc[t] - v;
    if (t == 255) bsum[blockIdx.x] = sc[255];
}

__global__ void k_scanB(int* __restrict__ bsum, int* __restrict__ row_ptr) {
    __shared__ int sc[512];
    int t = threadIdx.x;
    int v = (t < NB) ? bsum[t] : 0;
    sc[t] = v;
    __syncthreads();
    for (int off = 1; off < 512; off <<= 1) {
        int u = (t >= off) ? sc[t - off] : 0;
        __syncthreads();
        sc[t] += u;
        __syncthreads();
    }
    if (t < NB) bsum[t] = sc[t] - v;
    if (t == 0) row_ptr[NN] = EE;
}

__global__ void k_scanC(int* __restrict__ row_ptr, const int* __restrict__ bsum) {
    int i = blockIdx.x * blockDim.x + threadIdx.x;
    if (i < NN) row_ptr[i] += bsum[i >> 8];
}

// fill CSR: entry = { bits = (col<<6)|(row&63), dinv[col] }
__global__ void k_fill(const int* __restrict__ row, const int* __restrict__ col,
                       const float* __restrict__ dinv, const int* __restrict__ row_ptr,
                       int* __restrict__ fill, float2* __restrict__ csr) {
    int i = blockIdx.x * blockDim.x + threadIdx.x;
    int stride = gridDim.x * blockDim.x;
    for (int e = i; e < EE; e += stride) {
        int r = row[e], c = col[e];
        int pos = row_ptr[r] + atomicAdd(&fill[r], 1);
        csr[pos] = make_float2(__int_as_float((c << 6) | (r & 63)), dinv[c]);
    }
}

__global__ void k_copy_emb(const float* __restrict__ emb, float* __restrict__ out) {
    int i = blockIdx.x * blockDim.x + threadIdx.x;
    int stride = gridDim.x * blockDim.x;
    const float4* e4 = (const float4*)emb;
    float4* o4 = (float4*)out;
    const int total = NN * (DD / 4);
    for (int t = i; t < total; t += stride) {
        int n = t >> 4;
        int d4 = t & 15;
        o4[n * (OUTD / 4) + d4] = e4[t];
    }
}

// ---------------- fused per-layer ----------------
// Block = 256 threads = 4 waves, owns 64 consecutive nodes (CSR rows contiguous).
// Phase 1: waves split the block's flat edge range; 4 named-scalar gathers in
//          flight/wave; accumulate into LDS via ds_add_f32 (2-way aliasing, free).
//          lane0 accumulates cs[r] = sum dinv[col] for the bias term.
// Phase 2: S1 = dinv[r] * lds; P = S1 * x; 4x4 register microtile GEMM vs
//          W1^T/W2^T; bias weight c[n] = dinv[n] * cs[n].
// NOTE: __launch_bounds__(256,4) — (256,6) capped VGPR at 40 and spilled the
// gather state to scratch (round 3: +0.9 GB HBM traffic/layer, 2.3x slower).

__global__ void __launch_bounds__(256, 4) k_layer(
    const int* __restrict__ row_ptr, const float2* __restrict__ csr,
    const float* __restrict__ dinv,
    const float* __restrict__ W1, const float* __restrict__ b1,
    const float* __restrict__ W2, const float* __restrict__ b2,
    float* __restrict__ out, int layer)
{
    __shared__ float s1t[64][PAD];
    __shared__ float cs[64];

    const int lane = threadIdx.x & 63;
    const int wib  = threadIdx.x >> 6;
    const int n0   = blockIdx.x * 64;
    const float* __restrict__ x = out + layer * DD;      // row n at x[n*OUTD + d]

    #pragma unroll
    for (int i = 0; i < 16; ++i) s1t[wib * 16 + i][lane] = 0.f;
    if (threadIdx.x < 64) cs[threadIdx.x] = 0.f;
    __syncthreads();

    // ---- phase 1: flat edge gather ----
    const int beg = row_ptr[n0];
    const int end = row_ptr[n0 + 64];
    const int per = (end - beg + 3) >> 2;
    int e = beg + wib * per;
    const int e1 = min(end, e + per);

    for (; e + 4 <= e1; e += 4) {
        float2 q0 = csr[e], q1 = csr[e + 1], q2 = csr[e + 2], q3 = csr[e + 3];
        int c0 = __float_as_int(q0.x), c1 = __float_as_int(q1.x);
        int c2 = __float_as_int(q2.x), c3 = __float_as_int(q3.x);
        float v0 = q0.y * x[(c0 >> 6) * OUTD + lane];
        float v1 = q1.y * x[(c1 >> 6) * OUTD + lane];
        float v2 = q2.y * x[(c2 >> 6) * OUTD + lane];
        float v3 = q3.y * x[(c3 >> 6) * OUTD + lane];
        atomicAdd(&s1t[c0 & 63][lane], v0);
        atomicAdd(&s1t[c1 & 63][lane], v1);
        atomicAdd(&s1t[c2 & 63][lane], v2);
        atomicAdd(&s1t[c3 & 63][lane], v3);
        if (lane == 0) {
            atomicAdd(&cs[c0 & 63], q0.y);
            atomicAdd(&cs[c1 & 63], q1.y);
            atomicAdd(&cs[c2 & 63], q2.y);
            atomicAdd(&cs[c3 & 63], q3.y);
        }
    }
    for (; e < e1; ++e) {
        float2 q = csr[e];
        int c = __float_as_int(q.x);
        float v = q.y * x[(c >> 6) * OUTD + lane];
        atomicAdd(&s1t[c & 63][lane], v);
        if (lane == 0) atomicAdd(&cs[c & 63], q.y);
    }
    __syncthreads();

    // ---- phase 2: agg = S1@W1^T + (S1*x)@W2^T + c*(b1+b2) ----
    const int tf = threadIdx.x & 15;
    const int tn = threadIdx.x >> 4;
    const float* __restrict__ W1l = W1 + layer * DD * DD;
    const float* __restrict__ W2l = W2 + layer * DD * DD;

    float dv[4];
    #pragma unroll
    for (int i = 0; i < 4; ++i) dv[i] = dinv[n0 + 4 * tn + i];

    float acc[4][4];
    #pragma unroll
    for (int i = 0; i < 4; ++i)
        #pragma unroll
        for (int j = 0; j < 4; ++j) acc[i][j] = 0.f;

    for (int k4 = 0; k4 < 16; ++k4) {
        float4 a[4], p[4];
        #pragma unroll
        for (int i = 0; i < 4; ++i) {
            int nl = 4 * tn + i;
            float4 s  = *(const float4*)&s1t[nl][4 * k4];
            float4 xv = *(const float4*)&x[(size_t)(n0 + nl) * OUTD + 4 * k4];
            a[i].x = s.x * dv[i]; a[i].y = s.y * dv[i];
            a[i].z = s.z * dv[i]; a[i].w = s.w * dv[i];
            p[i].x = a[i].x * xv.x; p[i].y = a[i].y * xv.y;
            p[i].z = a[i].z * xv.z; p[i].w = a[i].w * xv.w;
        }
        #pragma unroll
        for (int j = 0; j < 4; ++j) {
            float4 wa = *(const float4*)&W1l[(4 * tf + j) * DD + 4 * k4];
            float4 wb = *(const float4*)&W2l[(4 * tf + j) * DD + 4 * k4];
            #pragma unroll
            for (int i = 0; i < 4; ++i) {
                acc[i][j] += a[i].x * wa.x + a[i].y * wa.y
                           + a[i].z * wa.z + a[i].w * wa.w
                           + p[i].x * wb.x + p[i].y * wb.y
                           + p[i].z * wb.z + p[i].w * wb.w;
            }
        }
    }

    float bbj[4];
    #pragma unroll
    for (int j = 0; j < 4; ++j) {
        int f = 4 * tf + j;
        bbj[j] = b1[layer * DD + f] + b2[layer * DD + f];
    }
    #pragma unroll
    for (int i = 0; i < 4; ++i) {
        int nl = 4 * tn + i;
        int n = n0 + nl;
        float c = dv[i] * cs[nl];
        float4 r;
        float t0 = acc[i][0] + c * bbj[0]; r.x = t0 >= 0.f ? t0 : 0.2f * t0;
        float t1 = acc[i][1] + c * bbj[1]; r.y = t1 >= 0.f ? t1 : 0.2f * t1;
        float t2 = acc[i][2] + c * bbj[2]; r.z = t2 >= 0.f ? t2 : 0.2f * t2;
        float t3 = acc[i][3] + c * bbj[3]; r.w = t3 >= 0.f ? t3 : 0.2f * t3;
        *(float4*)&out[(size_t)n * OUTD + (layer + 1) * DD + 4 * tf] = r;
    }
}

// ---------------- launch ----------------

extern "C" void kernel_launch(void* const* d_in, const int* in_sizes, int n_in,
                              void* d_out, int out_size, void* d_ws, size_t ws_size,
                              hipStream_t stream) {
    const int*   ei  = (const int*)d_in[0];
    const float* emb = (const float*)d_in[1];
    const float* W1  = (const float*)d_in[2];
    const float* b1  = (const float*)d_in[3];
    const float* W2  = (const float*)d_in[4];
    const float* b2  = (const float*)d_in[5];
    float* out = (float*)d_out;

    const int* row = ei;
    const int* col = ei + EE;

    // workspace layout
    float2* csr  = (float2*)d_ws;                 // EE float2 (8 MB)
    int* ibase   = (int*)(csr + EE);
    int* deg_i   = ibase;                         // NN
    int* cnt     = deg_i + NN;                    // NN
    int* fill    = cnt + NN;                      // NN
    int* row_ptr = fill + NN;                     // NN+1
    int* bsum    = row_ptr + NN + 1;              // 512
    float* dinv  = (float*)(bsum + 512);          // NN

    hipMemsetAsync(ibase, 0, (size_t)3 * NN * sizeof(int), stream);

    k_degcnt<<<1024, 256, 0, stream>>>(row, col, deg_i, cnt);
    k_dinv<<<NB, 256, 0, stream>>>(deg_i, dinv);
    k_scanA<<<NB, 256, 0, stream>>>(cnt, row_ptr, bsum);
    k_scanB<<<1, 512, 0, stream>>>(bsum, row_ptr);
    k_scanC<<<NB, 256, 0, stream>>>(row_ptr, bsum);
    k_fill<<<1024, 256, 0, stream>>>(row, col, dinv, row_ptr, fill, csr);
    k_copy_emb<<<2048, 256, 0, stream>>>(emb, out);

    for (int layer = 0; layer < NL; ++layer) {
        k_layer<<<NN / 64, 256, 0, stream>>>(row_ptr, csr, dinv,
                                             W1, b1, W2, b2, out, layer);
    }
}

// Round 7
// 776.219 us; speedup vs baseline: 2.2208x; 1.8984x over previous
//
#include <hip/hip_runtime.h>

#define NN 120000
#define DD 64
#define EE 1000000
#define NL 3
#define OUTD 256     // (NL+1)*DD
#define PAD 68       // LDS row pad: float4-aligned, 2-way bank aliasing only (free)
#define NB 469       // ceil(NN/256)

// ---------------- CSR build ----------------

__global__ void k_degcnt(const int* __restrict__ row, const int* __restrict__ col,
                         int* __restrict__ deg_i, int* __restrict__ cnt) {
    int i = blockIdx.x * blockDim.x + threadIdx.x;
    int stride = gridDim.x * blockDim.x;
    for (int e = i; e < EE; e += stride) {
        atomicAdd(&deg_i[col[e]], 1);
        atomicAdd(&cnt[row[e]], 1);
    }
}

__global__ void k_dinv(const int* __restrict__ deg_i, float* __restrict__ dinv) {
    int n = blockIdx.x * blockDim.x + threadIdx.x;
    if (n < NN) {
        int d = deg_i[n];
        dinv[n] = (d > 0) ? rsqrtf((float)d) : 0.0f;
    }
}

__global__ void k_scanA(const int* __restrict__ cnt, int* __restrict__ row_ptr,
                        int* __restrict__ bsum) {
    __shared__ int sc[256];
    int t = threadIdx.x;
    int i = blockIdx.x * 256 + t;
    int v = (i < NN) ? cnt[i] : 0;
    sc[t] = v;
    __syncthreads();
    for (int off = 1; off < 256; off <<= 1) {
        int u = (t >= off) ? sc[t - off] : 0;
        __syncthreads();
        sc[t] += u;
        __syncthreads();
    }
    if (i < NN) row_ptr[i] = sc[t] - v;
    if (t == 255) bsum[blockIdx.x] = sc[255];
}

__global__ void k_scanB(int* __restrict__ bsum, int* __restrict__ row_ptr) {
    __shared__ int sc[512];
    int t = threadIdx.x;
    int v = (t < NB) ? bsum[t] : 0;
    sc[t] = v;
    __syncthreads();
    for (int off = 1; off < 512; off <<= 1) {
        int u = (t >= off) ? sc[t - off] : 0;
        __syncthreads();
        sc[t] += u;
        __syncthreads();
    }
    if (t < NB) bsum[t] = sc[t] - v;
    if (t == 0) row_ptr[NN] = EE;
}

__global__ void k_scanC(int* __restrict__ row_ptr, const int* __restrict__ bsum) {
    int i = blockIdx.x * blockDim.x + threadIdx.x;
    if (i < NN) row_ptr[i] += bsum[i >> 8];
}

// fill SoA CSR: pkA[pos] = (col<<6)|(row&63), wtA[pos] = dinv[col]
__global__ void k_fill(const int* __restrict__ row, const int* __restrict__ col,
                       const float* __restrict__ dinv, const int* __restrict__ row_ptr,
                       int* __restrict__ fill, int* __restrict__ pkA,
                       float* __restrict__ wtA) {
    int i = blockIdx.x * blockDim.x + threadIdx.x;
    int stride = gridDim.x * blockDim.x;
    for (int e = i; e < EE; e += stride) {
        int r = row[e], c = col[e];
        int pos = row_ptr[r] + atomicAdd(&fill[r], 1);
        pkA[pos] = (c << 6) | (r & 63);
        wtA[pos] = dinv[c];
    }
}

__global__ void k_copy_emb(const float* __restrict__ emb, float* __restrict__ out) {
    int i = blockIdx.x * blockDim.x + threadIdx.x;
    int stride = gridDim.x * blockDim.x;
    const float4* e4 = (const float4*)emb;
    float4* o4 = (float4*)out;
    const int total = NN * (DD / 4);
    for (int t = i; t < total; t += stride) {
        int n = t >> 4;
        int d4 = t & 15;
        o4[n * (OUTD / 4) + d4] = e4[t];
    }
}

// ---------------- fused per-layer ----------------
// Block = 4 waves, owns 64 consecutive nodes. Wave w owns nodes [w*16, w*16+16)
// whose CSR edges are one contiguous, row-sorted range -> wave walks it FLAT,
// 8 gathers in flight, REGISTER accumulation; on (wave-uniform) row change it
// flushes acc to its own LDS rows with a plain store. No atomics anywhere.
// (Round 6 lesson: LDS float atomicAdd = CAS loop, 2x slower. Round 2 lesson:
// per-node unrolled loops degenerate to scalar tail at mean degree 8.3.)
// Phase 2: S1 = dinv[r]*lds; P = S1*x; 4x4 register microtile GEMM vs W1^T/W2^T.
// NOTE: keep __launch_bounds__(256,4); (256,6) spilled (round 3: +0.9 GB/layer).

__global__ void __launch_bounds__(256, 4) k_layer(
    const int* __restrict__ row_ptr, const int* __restrict__ pkA,
    const float* __restrict__ wtA, const float* __restrict__ dinv,
    const float* __restrict__ W1, const float* __restrict__ b1,
    const float* __restrict__ W2, const float* __restrict__ b2,
    float* __restrict__ out, int layer)
{
    __shared__ float s1t[64][PAD];
    __shared__ float cs[64];

    const int lane = threadIdx.x & 63;
    const int wib  = threadIdx.x >> 6;
    const int n0   = blockIdx.x * 64;
    const float* __restrict__ x = out + layer * DD;      // row n at x[n*OUTD + d]

    // each wave inits ONLY its own rows -> no barrier needed before phase 1
    #pragma unroll
    for (int i = 0; i < 16; ++i) s1t[wib * 16 + i][lane] = 0.f;
    if (lane < 16) cs[wib * 16 + lane] = 0.f;

    // ---- phase 1: flat gather over this wave's 16 nodes' edge range ----
    const int nbase = n0 + wib * 16;
    int e        = __builtin_amdgcn_readfirstlane(row_ptr[nbase]);
    const int ee = __builtin_amdgcn_readfirstlane(row_ptr[nbase + 16]);

    float acc = 0.f, cacc = 0.f;
    int rcur = (e < ee) ? (pkA[e] & 63) : -1;

#define STEP(p_, w_, v_)                                                     \
    {   int r_ = (p_) & 63;                                                  \
        if (r_ != rcur) {                                                    \
            s1t[rcur][lane] = acc;                                           \
            if (lane == 0) cs[rcur] = cacc;                                  \
            rcur = r_; acc = 0.f; cacc = 0.f;                                \
        }                                                                    \
        acc = fmaf((w_), (v_), acc); cacc += (w_); }

    for (; e + 8 <= ee; e += 8) {
        int p0 = pkA[e],     p1 = pkA[e + 1], p2 = pkA[e + 2], p3 = pkA[e + 3];
        int p4 = pkA[e + 4], p5 = pkA[e + 5], p6 = pkA[e + 6], p7 = pkA[e + 7];
        float w0 = wtA[e],     w1 = wtA[e + 1], w2 = wtA[e + 2], w3 = wtA[e + 3];
        float w4 = wtA[e + 4], w5 = wtA[e + 5], w6 = wtA[e + 6], w7 = wtA[e + 7];
        float v0 = x[(p0 >> 6) * OUTD + lane];
        float v1 = x[(p1 >> 6) * OUTD + lane];
        float v2 = x[(p2 >> 6) * OUTD + lane];
        float v3 = x[(p3 >> 6) * OUTD + lane];
        float v4 = x[(p4 >> 6) * OUTD + lane];
        float v5 = x[(p5 >> 6) * OUTD + lane];
        float v6 = x[(p6 >> 6) * OUTD + lane];
        float v7 = x[(p7 >> 6) * OUTD + lane];
        STEP(p0, w0, v0) STEP(p1, w1, v1) STEP(p2, w2, v2) STEP(p3, w3, v3)
        STEP(p4, w4, v4) STEP(p5, w5, v5) STEP(p6, w6, v6) STEP(p7, w7, v7)
    }
    for (; e < ee; ++e) {
        int p = pkA[e];
        float w = wtA[e];
        float v = x[(p >> 6) * OUTD + lane];
        STEP(p, w, v)
    }
    if (rcur >= 0) {
        s1t[rcur][lane] = acc;
        if (lane == 0) cs[rcur] = cacc;
    }
#undef STEP
    __syncthreads();

    // ---- phase 2: agg = S1@W1^T + (S1*x)@W2^T + c*(b1+b2) ----
    const int tf = threadIdx.x & 15;
    const int tn = threadIdx.x >> 4;
    const float* __restrict__ W1l = W1 + layer * DD * DD;
    const float* __restrict__ W2l = W2 + layer * DD * DD;

    float dv[4];
    #pragma unroll
    for (int i = 0; i < 4; ++i) dv[i] = dinv[n0 + 4 * tn + i];

    float acc2[4][4];
    #pragma unroll
    for (int i = 0; i < 4; ++i)
        #pragma unroll
        for (int j = 0; j < 4; ++j) acc2[i][j] = 0.f;

    for (int k4 = 0; k4 < 16; ++k4) {
        float4 a[4], p[4];
        #pragma unroll
        for (int i = 0; i < 4; ++i) {
            int nl = 4 * tn + i;
            float4 s  = *(const float4*)&s1t[nl][4 * k4];
            float4 xv = *(const float4*)&x[(size_t)(n0 + nl) * OUTD + 4 * k4];
            a[i].x = s.x * dv[i]; a[i].y = s.y * dv[i];
            a[i].z = s.z * dv[i]; a[i].w = s.w * dv[i];
            p[i].x = a[i].x * xv.x; p[i].y = a[i].y * xv.y;
            p[i].z = a[i].z * xv.z; p[i].w = a[i].w * xv.w;
        }
        #pragma unroll
        for (int j = 0; j < 4; ++j) {
            float4 wa = *(const float4*)&W1l[(4 * tf + j) * DD + 4 * k4];
            float4 wb = *(const float4*)&W2l[(4 * tf + j) * DD + 4 * k4];
            #pragma unroll
            for (int i = 0; i < 4; ++i) {
                acc2[i][j] += a[i].x * wa.x + a[i].y * wa.y
                            + a[i].z * wa.z + a[i].w * wa.w
                            + p[i].x * wb.x + p[i].y * wb.y
                            + p[i].z * wb.z + p[i].w * wb.w;
            }
        }
    }

    float bbj[4];
    #pragma unroll
    for (int j = 0; j < 4; ++j) {
        int f = 4 * tf + j;
        bbj[j] = b1[layer * DD + f] + b2[layer * DD + f];
    }
    #pragma unroll
    for (int i = 0; i < 4; ++i) {
        int nl = 4 * tn + i;
        int n = n0 + nl;
        float c = dv[i] * cs[nl];
        float4 r;
        float t0 = acc2[i][0] + c * bbj[0]; r.x = t0 >= 0.f ? t0 : 0.2f * t0;
        float t1 = acc2[i][1] + c * bbj[1]; r.y = t1 >= 0.f ? t1 : 0.2f * t1;
        float t2 = acc2[i][2] + c * bbj[2]; r.z = t2 >= 0.f ? t2 : 0.2f * t2;
        float t3 = acc2[i][3] + c * bbj[3]; r.w = t3 >= 0.f ? t3 : 0.2f * t3;
        *(float4*)&out[(size_t)n * OUTD + (layer + 1) * DD + 4 * tf] = r;
    }
}

// ---------------- launch ----------------

extern "C" void kernel_launch(void* const* d_in, const int* in_sizes, int n_in,
                              void* d_out, int out_size, void* d_ws, size_t ws_size,
                              hipStream_t stream) {
    const int*   ei  = (const int*)d_in[0];
    const float* emb = (const float*)d_in[1];
    const float* W1  = (const float*)d_in[2];
    const float* b1  = (const float*)d_in[3];
    const float* W2  = (const float*)d_in[4];
    const float* b2  = (const float*)d_in[5];
    float* out = (float*)d_out;

    const int* row = ei;
    const int* col = ei + EE;

    // workspace layout (SoA CSR)
    int*   pkA   = (int*)d_ws;                    // EE (4 MB)
    float* wtA   = (float*)(pkA + EE);            // EE (4 MB)
    int* ibase   = (int*)(wtA + EE);
    int* deg_i   = ibase;                         // NN
    int* cnt     = deg_i + NN;                    // NN
    int* fill    = cnt + NN;                      // NN
    int* row_ptr = fill + NN;                     // NN+1
    int* bsum    = row_ptr + NN + 1;              // 512
    float* dinv  = (float*)(bsum + 512);          // NN

    hipMemsetAsync(ibase, 0, (size_t)3 * NN * sizeof(int), stream);

    k_degcnt<<<1024, 256, 0, stream>>>(row, col, deg_i, cnt);
    k_dinv<<<NB, 256, 0, stream>>>(deg_i, dinv);
    k_scanA<<<NB, 256, 0, stream>>>(cnt, row_ptr, bsum);
    k_scanB<<<1, 512, 0, stream>>>(bsum, row_ptr);
    k_scanC<<<NB, 256, 0, stream>>>(row_ptr, bsum);
    k_fill<<<1024, 256, 0, stream>>>(row, col, dinv, row_ptr, fill, pkA, wtA);
    k_copy_emb<<<2048, 256, 0, stream>>>(emb, out);

    for (int layer = 0; layer < NL; ++layer) {
        k_layer<<<NN / 64, 256, 0, stream>>>(row_ptr, pkA, wtA, dinv,
                                             W1, b1, W2, b2, out, layer);
    }
}